// Round 8
// baseline (195.499 us; speedup 1.0000x reference)
//
#include <hip/hip_runtime.h>
#include <hip/hip_fp16.h>

#define NODE_DIM 128
#define EDGE_DIM 128
#define N_RADIAL 16
#define MAXZ     100

typedef _Float16 h2  __attribute__((ext_vector_type(2)));
typedef float    fx2 __attribute__((ext_vector_type(2)));
typedef float    fx4 __attribute__((ext_vector_type(4)));

__device__ __forceinline__ float fdot2f(h2 a, h2 b, float c) {
#if __has_builtin(__builtin_amdgcn_fdot2)
    return __builtin_amdgcn_fdot2(a, b, c, false);
#else
    return c + (float)a.x * (float)b.x + (float)a.y * (float)b.y;
#endif
}

// ---------------------------------------------------------------------------
// Precompute.  Blocks [0,max_z): fp16 node tables
//   t1[r][d] = sum_k embed[r][k]*edge_w[k][d] + edge_b[d]
//   t2[r][d] = sum_k embed[r][k]*edge_w[128+k][d]
// Blocks [max_z, max_z+8): pair-packed fp16 rbf matrix
//   w3h[kk*128+d] = ( w3c[2kk][d], w3c[2kk+1][d] ),  w3c = rbf_w @ W3
// ---------------------------------------------------------------------------
__global__ void precompute_tables(const float* __restrict__ embed_table,
                                  const float* __restrict__ edge_w,
                                  const float* __restrict__ edge_b,
                                  const float* __restrict__ rbf_w,
                                  __half* __restrict__ tH,
                                  h2* __restrict__ w3h,
                                  int max_z) {
    const int d = threadIdx.x;
    if ((int)blockIdx.x < max_z) {
        const int r = blockIdx.x;
        float s1 = edge_b[d];
        float s2 = 0.0f;
        const float* er = embed_table + (long)r * NODE_DIM;
#pragma unroll 8
        for (int k = 0; k < NODE_DIM; ++k) {
            const float e = er[k];
            s1 += e * edge_w[(long)k * EDGE_DIM + d];
            s2 += e * edge_w[(long)(NODE_DIM + k) * EDGE_DIM + d];
        }
        tH[(long)r * EDGE_DIM + d]          = __float2half(s1);
        tH[(long)(MAXZ + r) * EDGE_DIM + d] = __float2half(s2);
    } else {
        const int kk = blockIdx.x - max_z;    // 0..7
        const float* ra = rbf_w + (long)(2 * kk)     * EDGE_DIM;
        const float* rb = rbf_w + (long)(2 * kk + 1) * EDGE_DIM;
        float sa = 0.0f, sb = 0.0f;
#pragma unroll 8
        for (int k = 0; k < EDGE_DIM; ++k) {
            const float wkd = edge_w[(long)(2 * NODE_DIM + k) * EDGE_DIM + d];
            sa += ra[k] * wkd;
            sb += rb[k] * wkd;
        }
        h2 v; v.x = (_Float16)sa; v.y = (_Float16)sb;
        w3h[kk * EDGE_DIM + d] = v;
    }
}

// ---------------------------------------------------------------------------
// zpair[e] = z[idx_j[e]] | (z[idx_i[e]] << 16)
// ---------------------------------------------------------------------------
__global__ void precompute_zpair(const int* __restrict__ z,
                                 const int* __restrict__ idx_i,
                                 const int* __restrict__ idx_j,
                                 int* __restrict__ zpair,
                                 int n_edges) {
    const int e = blockIdx.x * blockDim.x + threadIdx.x;
    if (e < n_edges) {
        const int zj = z[idx_j[e]];
        const int zi = z[idx_i[e]];
        zpair[e] = (zj & 0xffff) | (zi << 16);
    }
}

// ---------------------------------------------------------------------------
// Main kernel: NO LDS, no barriers.  One edge per wave per iteration; each
// lane owns 2 floats of the 128-wide output row.  fp16 tables + pair-packed
// fp16 w3c read from global (L1/L2-resident); rbf fp32 streamed; fdot2
// accumulates in fp32.  Register pipeline: zpair depth-2, table/rbf depth-1.
// ---------------------------------------------------------------------------
template <bool PRE>
__global__ void __launch_bounds__(256, 7) edge_main(
        const float* __restrict__ rbf,
        const int*   __restrict__ zpair,
        const int*   __restrict__ z,
        const int*   __restrict__ idx_i,
        const int*   __restrict__ idx_j,
        const h2*    __restrict__ tab,     // 2*MAXZ rows of 64 h2
        const h2*    __restrict__ w3h,     // 8*128 h2
        float* __restrict__ out,
        int n_edges) {
    const int lane = threadIdx.x & 63;
    const int wv   = __builtin_amdgcn_readfirstlane(threadIdx.x >> 6);
    const int gw   = blockIdx.x * 4 + wv;           // global wave id (scalar)
    const int W    = gridDim.x * 4;
    const int elo  = (int)(((long)gw * n_edges) / W);
    const int ehi  = (int)(((long)(gw + 1) * n_edges) / W);
    if (elo >= ehi) return;

    // this lane's 2 output columns of w3c: 16 h2 (coalesced dwordx2 loads)
    h2 w[16];
#pragma unroll
    for (int kk = 0; kk < 8; ++kk) {
        w[2 * kk]     = w3h[kk * EDGE_DIM + 2 * lane];
        w[2 * kk + 1] = w3h[kk * EDGE_DIM + 2 * lane + 1];
    }

    const fx4* rbf4 = (const fx4*)rbf;

#define GETZP(E) (PRE ? zpair[(E)] \
                      : ((z[idx_j[(E)]] & 0xffff) | (z[idx_i[(E)]] << 16)))

    // ---- prologue: fill pipeline ----
    const int e1p = (elo + 1 < ehi) ? elo + 1 : elo;
    int zp0 = GETZP(elo);       // for edge e   (compute)
    int zp1 = GETZP(e1p);       // for edge e+1 (table issue next iter)
    // current edge's data:
    h2 tj0 = tab[(zp0 & 0xffff) * 64 + lane];
    h2 ti0 = tab[(MAXZ + (zp0 >> 16)) * 64 + lane];
    h2 rb0[8];
    {
        fx4 a = rbf4[(long)elo * 4 + 0], b = rbf4[(long)elo * 4 + 1];
        fx4 c = rbf4[(long)elo * 4 + 2], d = rbf4[(long)elo * 4 + 3];
        rb0[0].x = (_Float16)a.x; rb0[0].y = (_Float16)a.y;
        rb0[1].x = (_Float16)a.z; rb0[1].y = (_Float16)a.w;
        rb0[2].x = (_Float16)b.x; rb0[2].y = (_Float16)b.y;
        rb0[3].x = (_Float16)b.z; rb0[3].y = (_Float16)b.w;
        rb0[4].x = (_Float16)c.x; rb0[4].y = (_Float16)c.y;
        rb0[5].x = (_Float16)c.z; rb0[5].y = (_Float16)c.w;
        rb0[6].x = (_Float16)d.x; rb0[6].y = (_Float16)d.y;
        rb0[7].x = (_Float16)d.z; rb0[7].y = (_Float16)d.w;
    }

#pragma clang loop unroll(disable)
    for (int e = elo; e < ehi; ++e) {
        const int en1 = (e + 1 < ehi) ? e + 1 : ehi - 1;
        const int en2 = (e + 2 < ehi) ? e + 2 : ehi - 1;

        // issue depth-2 zpair and depth-1 table/rbf loads
        const int zp2 = GETZP(en2);
        h2 tj1 = tab[(zp1 & 0xffff) * 64 + lane];
        h2 ti1 = tab[(MAXZ + (zp1 >> 16)) * 64 + lane];
        const fx4 na = rbf4[(long)en1 * 4 + 0];
        const fx4 nb = rbf4[(long)en1 * 4 + 1];
        const fx4 nc = rbf4[(long)en1 * 4 + 2];
        const fx4 nd = rbf4[(long)en1 * 4 + 3];

        // ---- compute edge e ----
        fx2 acc;
        {
            const h2 t = tj0 + ti0;            // v_pk_add_f16
            acc.x = (float)t.x;
            acc.y = (float)t.y;
        }
#pragma unroll
        for (int kk = 0; kk < 8; ++kk) {
            acc.x = fdot2f(rb0[kk], w[2 * kk],     acc.x);
            acc.y = fdot2f(rb0[kk], w[2 * kk + 1], acc.y);
        }
        fx2 o;
        o.x = acc.x * __builtin_amdgcn_rcpf(1.0f + __expf(-acc.x));
        o.y = acc.y * __builtin_amdgcn_rcpf(1.0f + __expf(-acc.y));
        *(fx2*)(out + (size_t)e * EDGE_DIM + 2 * lane) = o;

        // ---- rotate pipeline ----
        zp0 = zp1; zp1 = zp2;
        tj0 = tj1; ti0 = ti1;
        rb0[0].x = (_Float16)na.x; rb0[0].y = (_Float16)na.y;
        rb0[1].x = (_Float16)na.z; rb0[1].y = (_Float16)na.w;
        rb0[2].x = (_Float16)nb.x; rb0[2].y = (_Float16)nb.y;
        rb0[3].x = (_Float16)nb.z; rb0[3].y = (_Float16)nb.w;
        rb0[4].x = (_Float16)nc.x; rb0[4].y = (_Float16)nc.y;
        rb0[5].x = (_Float16)nc.z; rb0[5].y = (_Float16)nc.w;
        rb0[6].x = (_Float16)nd.x; rb0[6].y = (_Float16)nd.y;
        rb0[7].x = (_Float16)nd.z; rb0[7].y = (_Float16)nd.w;
    }
#undef GETZP
}

extern "C" void kernel_launch(void* const* d_in, const int* in_sizes, int n_in,
                              void* d_out, int out_size, void* d_ws, size_t ws_size,
                              hipStream_t stream) {
    const int*   zp          = (const int*)  d_in[0];
    const float* rbf         = (const float*)d_in[1];
    const int*   idx_i       = (const int*)  d_in[2];
    const int*   idx_j       = (const int*)  d_in[3];
    const float* embed_table = (const float*)d_in[4];
    const float* rbf_w       = (const float*)d_in[5];
    const float* edge_w      = (const float*)d_in[6];
    const float* edge_b      = (const float*)d_in[7];

    int max_z = in_sizes[4] / NODE_DIM;           // 100
    if (max_z > MAXZ) max_z = MAXZ;
    const int n_edges = in_sizes[2];              // 800000

    const size_t tab_bytes = (size_t)2 * MAXZ * EDGE_DIM * sizeof(__half); // 51200
    const size_t w3h_bytes = (size_t)8 * EDGE_DIM * sizeof(h2);            // 4096
    __half* tH    = (__half*)d_ws;
    h2*     w3h   = (h2*)((char*)d_ws + tab_bytes);
    int*    zpair = (int*)((char*)d_ws + tab_bytes + w3h_bytes);
    const int use_zpair =
        (ws_size >= tab_bytes + w3h_bytes + (size_t)n_edges * sizeof(int)) ? 1 : 0;
    float* out = (float*)d_out;

    precompute_tables<<<max_z + 8, EDGE_DIM, 0, stream>>>(
        embed_table, edge_w, edge_b, rbf_w, tH, w3h, max_z);
    if (use_zpair)
        precompute_zpair<<<(n_edges + 255) / 256, 256, 0, stream>>>(
            zp, idx_i, idx_j, zpair, n_edges);

    const int grid = 2048;   // 8192 waves; ~98 contiguous edges per wave
    if (use_zpair)
        edge_main<true><<<grid, 256, 0, stream>>>(rbf, zpair, zp, idx_i, idx_j,
                                                  (const h2*)tH, w3h, out, n_edges);
    else
        edge_main<false><<<grid, 256, 0, stream>>>(rbf, zpair, zp, idx_i, idx_j,
                                                   (const h2*)tH, w3h, out, n_edges);
}

// Round 9
// 184.366 us; speedup vs baseline: 1.0604x; 1.0604x over previous
//
#include <hip/hip_runtime.h>
#include <hip/hip_fp16.h>

#define NODE_DIM 128
#define EDGE_DIM 128
#define N_RADIAL 16
#define MAXZ     100
#define BLOCK    512
#define NWAVE    (BLOCK / 64)

typedef _Float16 h2  __attribute__((ext_vector_type(2)));
typedef _Float16 h4  __attribute__((ext_vector_type(4)));
typedef float    fx4 __attribute__((ext_vector_type(4)));

__device__ __forceinline__ float fdot2f(h2 a, h2 b, float c) {
#if __has_builtin(__builtin_amdgcn_fdot2)
    return __builtin_amdgcn_fdot2(a, b, c, false);
#else
    return c + (float)a.x * (float)b.x + (float)a.y * (float)b.y;
#endif
}

__device__ __forceinline__ h2 pk16(float x, float y) {
#if __has_builtin(__builtin_amdgcn_cvt_pkrtz)
    return __builtin_bit_cast(h2, __builtin_amdgcn_cvt_pkrtz(x, y));
#else
    h2 v; v.x = (_Float16)x; v.y = (_Float16)y; return v;
#endif
}

// ---------------------------------------------------------------------------
// Precompute.  Blocks [0,max_z): fp16 node tables
//   t1[r][d] = sum_k embed[r][k]*edge_w[k][d] + edge_b[d]
//   t2[r][d] = sum_k embed[r][k]*edge_w[128+k][d]
// Blocks [max_z, max_z+8): pair-packed fp16 rbf matrix
//   w3h[kk*128+d] = ( w3c[2kk][d], w3c[2kk+1][d] ),  w3c = rbf_w @ W3
// ---------------------------------------------------------------------------
__global__ void precompute_tables(const float* __restrict__ embed_table,
                                  const float* __restrict__ edge_w,
                                  const float* __restrict__ edge_b,
                                  const float* __restrict__ rbf_w,
                                  __half* __restrict__ tH,
                                  h2* __restrict__ w3h,
                                  int max_z) {
    const int d = threadIdx.x;
    if ((int)blockIdx.x < max_z) {
        const int r = blockIdx.x;
        float s1 = edge_b[d];
        float s2 = 0.0f;
        const float* er = embed_table + (long)r * NODE_DIM;
#pragma unroll 8
        for (int k = 0; k < NODE_DIM; ++k) {
            const float e = er[k];
            s1 += e * edge_w[(long)k * EDGE_DIM + d];
            s2 += e * edge_w[(long)(NODE_DIM + k) * EDGE_DIM + d];
        }
        tH[(long)r * EDGE_DIM + d]          = __float2half(s1);
        tH[(long)(MAXZ + r) * EDGE_DIM + d] = __float2half(s2);
    } else {
        const int kk = blockIdx.x - max_z;    // 0..7
        const float* ra = rbf_w + (long)(2 * kk)     * EDGE_DIM;
        const float* rb = rbf_w + (long)(2 * kk + 1) * EDGE_DIM;
        float sa = 0.0f, sb = 0.0f;
#pragma unroll 8
        for (int k = 0; k < EDGE_DIM; ++k) {
            const float wkd = edge_w[(long)(2 * NODE_DIM + k) * EDGE_DIM + d];
            sa += ra[k] * wkd;
            sb += rb[k] * wkd;
        }
        h2 v; v.x = (_Float16)sa; v.y = (_Float16)sb;
        w3h[kk * EDGE_DIM + d] = v;
    }
}

// ---------------------------------------------------------------------------
// zpair[e] = z[idx_j[e]] | (z[idx_i[e]] << 16)
// ---------------------------------------------------------------------------
__global__ void precompute_zpair(const int* __restrict__ z,
                                 const int* __restrict__ idx_i,
                                 const int* __restrict__ idx_j,
                                 int* __restrict__ zpair,
                                 int n_edges) {
    const int e = blockIdx.x * blockDim.x + threadIdx.x;
    if (e < n_edges) {
        const int zj = z[idx_j[e]];
        const int zi = z[idx_i[e]];
        zpair[e] = (zj & 0xffff) | (zi << 16);
    }
}

// ---------------------------------------------------------------------------
// Main kernel: LDS = fp16 table ONLY (51.2 KB -> 3 blocks/CU, 24 waves/CU).
// Per wave: contiguous edges, 2 per step (lanes 0-31 edge e, 32-63 e+1),
// lane owns one float4 of the 128-wide output row.  rbf read direct from
// global (broadcast per 32-group), converted to packed fp16; contraction by
// v_dot2_f32_f16 against pair-packed w3h held in 32 VGPRs.  zpair has a
// depth-2 register pipeline; unroll(2) lets the compiler interleave steps.
// ---------------------------------------------------------------------------
template <bool PRE>
__global__ void __launch_bounds__(BLOCK, 6) edge_main(
        const float* __restrict__ rbf,
        const int*   __restrict__ zpair,
        const int*   __restrict__ z,
        const int*   __restrict__ idx_i,
        const int*   __restrict__ idx_j,
        const h2*    __restrict__ tabg,    // 2*MAXZ rows of 64 h2
        const h2*    __restrict__ w3h,     // 8*128 h2
        float* __restrict__ out,
        int n_edges) {
    __shared__ h2 sTab[2 * MAXZ * 64];                 // 51200 B, only LDS

    const int tid  = threadIdx.x;
    const int lane = tid & 63;
    const int sub  = lane & 31;
    const int half = lane >> 5;

    // pair-packed w slice for this lane's 4 output cols: w[kk][c], 32 VGPRs
    h2 w[8][4];
#pragma unroll
    for (int kk = 0; kk < 8; ++kk) {
        const uint4 u = *reinterpret_cast<const uint4*>(
            &w3h[kk * EDGE_DIM + (sub << 2)]);
        w[kk][0] = __builtin_bit_cast(h2, u.x);
        w[kk][1] = __builtin_bit_cast(h2, u.y);
        w[kk][2] = __builtin_bit_cast(h2, u.z);
        w[kk][3] = __builtin_bit_cast(h2, u.w);
    }

    // cooperative copy of the table into LDS (3200 uint4)
    {
        const uint4* src = reinterpret_cast<const uint4*>(tabg);
        uint4*       dst = reinterpret_cast<uint4*>(sTab);
        for (int i = tid; i < (2 * MAXZ * EDGE_DIM) / 8; i += BLOCK)
            dst[i] = src[i];
    }
    __syncthreads();   // only barrier

    const int W   = gridDim.x * NWAVE;
    const int gw  = blockIdx.x * NWAVE + (tid >> 6);
    const int elo = (int)(((long)gw * n_edges) / W);
    const int ehi = (int)(((long)(gw + 1) * n_edges) / W);
    if (elo >= ehi) return;

    const fx4* rbf4 = reinterpret_cast<const fx4*>(rbf);
    const int  nm1  = n_edges - 1;

#define GETZP(E) (PRE ? zpair[(E)] \
                      : ((z[idx_j[(E)]] & 0xffff) | (z[idx_i[(E)]] << 16)))
#define CLAMP(E) ((E) < nm1 ? (E) : nm1)

    // depth-2 zpair pipeline (this lane's edge each step advances by 2)
    int zpA = GETZP(CLAMP(elo + half));        // for step 0
    int zpB = GETZP(CLAMP(elo + 2 + half));    // for step 1

#pragma unroll 2
    for (int e2 = elo; e2 < ehi; e2 += 2) {
        const int el = e2 + half;              // this lane's edge
        const int ec = CLAMP(el);

        // issue zpair for step +2
        const int zpN = GETZP(CLAMP(e2 + 4 + half));

        // table rows for current edge (LDS, 8 B each)
        const int zj = zpA & 0xffff;
        const int zi = zpA >> 16;
        const h4 tj = *reinterpret_cast<const h4*>(&sTab[zj * 64 + (sub << 1)]);
        const h4 ti = *reinterpret_cast<const h4*>(
            &sTab[(MAXZ + zi) * 64 + (sub << 1)]);

        // rbf row for current edge (broadcast within the 32-group)
        const fx4 a = rbf4[(long)ec * 4 + 0];
        const fx4 b = rbf4[(long)ec * 4 + 1];
        const fx4 c = rbf4[(long)ec * 4 + 2];
        const fx4 d = rbf4[(long)ec * 4 + 3];
        h2 rb[8];
        rb[0] = pk16(a.x, a.y); rb[1] = pk16(a.z, a.w);
        rb[2] = pk16(b.x, b.y); rb[3] = pk16(b.z, b.w);
        rb[4] = pk16(c.x, c.y); rb[5] = pk16(c.z, c.w);
        rb[6] = pk16(d.x, d.y); rb[7] = pk16(d.z, d.w);

        // acc init = t1[zj] + t2[zi]  (packed fp16 add, then widen)
        const h4 t = tj + ti;
        float a0 = (float)t[0], a1 = (float)t[1];
        float a2 = (float)t[2], a3 = (float)t[3];

#pragma unroll
        for (int kk = 0; kk < 8; ++kk) {
            a0 = fdot2f(rb[kk], w[kk][0], a0);
            a1 = fdot2f(rb[kk], w[kk][1], a1);
            a2 = fdot2f(rb[kk], w[kk][2], a2);
            a3 = fdot2f(rb[kk], w[kk][3], a3);
        }

        // swish via fast rcp
        fx4 o;
        o.x = a0 * __builtin_amdgcn_rcpf(1.0f + __expf(-a0));
        o.y = a1 * __builtin_amdgcn_rcpf(1.0f + __expf(-a1));
        o.z = a2 * __builtin_amdgcn_rcpf(1.0f + __expf(-a2));
        o.w = a3 * __builtin_amdgcn_rcpf(1.0f + __expf(-a3));

        if (el < ehi)
            *reinterpret_cast<fx4*>(&out[(size_t)el * EDGE_DIM + (sub << 2)]) = o;

        zpA = zpB; zpB = zpN;
    }
#undef GETZP
#undef CLAMP
}

extern "C" void kernel_launch(void* const* d_in, const int* in_sizes, int n_in,
                              void* d_out, int out_size, void* d_ws, size_t ws_size,
                              hipStream_t stream) {
    const int*   zp          = (const int*)  d_in[0];
    const float* rbf         = (const float*)d_in[1];
    const int*   idx_i       = (const int*)  d_in[2];
    const int*   idx_j       = (const int*)  d_in[3];
    const float* embed_table = (const float*)d_in[4];
    const float* rbf_w       = (const float*)d_in[5];
    const float* edge_w      = (const float*)d_in[6];
    const float* edge_b      = (const float*)d_in[7];

    int max_z = in_sizes[4] / NODE_DIM;           // 100
    if (max_z > MAXZ) max_z = MAXZ;
    const int n_edges = in_sizes[2];              // 800000

    const size_t tab_bytes = (size_t)2 * MAXZ * EDGE_DIM * sizeof(__half); // 51200
    const size_t w3h_bytes = (size_t)8 * EDGE_DIM * sizeof(h2);            // 4096
    __half* tH    = (__half*)d_ws;
    h2*     w3h   = (h2*)((char*)d_ws + tab_bytes);
    int*    zpair = (int*)((char*)d_ws + tab_bytes + w3h_bytes);
    const int use_zpair =
        (ws_size >= tab_bytes + w3h_bytes + (size_t)n_edges * sizeof(int)) ? 1 : 0;
    float* out = (float*)d_out;

    precompute_tables<<<max_z + 8, EDGE_DIM, 0, stream>>>(
        embed_table, edge_w, edge_b, rbf_w, tH, w3h, max_z);
    if (use_zpair)
        precompute_zpair<<<(n_edges + 255) / 256, 256, 0, stream>>>(
            zp, idx_i, idx_j, zpair, n_edges);

    const int grid = 768;   // 3 blocks/CU resident (LDS 51.2 KB each)
    if (use_zpair)
        edge_main<true><<<grid, BLOCK, 0, stream>>>(rbf, zpair, zp, idx_i, idx_j,
                                                    (const h2*)tH, w3h, out, n_edges);
    else
        edge_main<false><<<grid, BLOCK, 0, stream>>>(rbf, zpair, zp, idx_i, idx_j,
                                                     (const h2*)tH, w3h, out, n_edges);
}

// Round 10
// 127.302 us; speedup vs baseline: 1.5357x; 1.4483x over previous
//
#include <hip/hip_runtime.h>
#include <hip/hip_fp16.h>

#define NODE_DIM 128
#define EDGE_DIM 128
#define N_RADIAL 16
#define MAXZ     100
#define BLOCK    512
#define NWAVE    (BLOCK / 64)
#define MC       16            // edges per wave-private chunk (regs, not LDS)

typedef _Float16 h2  __attribute__((ext_vector_type(2)));
typedef _Float16 h4  __attribute__((ext_vector_type(4)));
typedef float    fx4 __attribute__((ext_vector_type(4)));

__device__ __forceinline__ float fdot2f(h2 a, h2 b, float c) {
#if __has_builtin(__builtin_amdgcn_fdot2)
    return __builtin_amdgcn_fdot2(a, b, c, false);
#else
    return c + (float)a.x * (float)b.x + (float)a.y * (float)b.y;
#endif
}

__device__ __forceinline__ int pk16i(float x, float y) {
#if __has_builtin(__builtin_amdgcn_cvt_pkrtz)
    return __builtin_bit_cast(int, __builtin_amdgcn_cvt_pkrtz(x, y));
#else
    h2 v; v.x = (_Float16)x; v.y = (_Float16)y;
    return __builtin_bit_cast(int, v);
#endif
}

// ---------------------------------------------------------------------------
// Precompute.  Blocks [0,max_z): fp16 node tables.
// Blocks [max_z, max_z+8): pair-packed fp16 rbf matrix
//   w3h[kk*128+d] = ( w3c[2kk][d], w3c[2kk+1][d] ),  w3c = rbf_w @ W3
// ---------------------------------------------------------------------------
__global__ void precompute_tables(const float* __restrict__ embed_table,
                                  const float* __restrict__ edge_w,
                                  const float* __restrict__ edge_b,
                                  const float* __restrict__ rbf_w,
                                  __half* __restrict__ tH,
                                  h2* __restrict__ w3h,
                                  int max_z) {
    const int d = threadIdx.x;
    if ((int)blockIdx.x < max_z) {
        const int r = blockIdx.x;
        float s1 = edge_b[d];
        float s2 = 0.0f;
        const float* er = embed_table + (long)r * NODE_DIM;
#pragma unroll 8
        for (int k = 0; k < NODE_DIM; ++k) {
            const float e = er[k];
            s1 += e * edge_w[(long)k * EDGE_DIM + d];
            s2 += e * edge_w[(long)(NODE_DIM + k) * EDGE_DIM + d];
        }
        tH[(long)r * EDGE_DIM + d]          = __float2half(s1);
        tH[(long)(MAXZ + r) * EDGE_DIM + d] = __float2half(s2);
    } else {
        const int kk = blockIdx.x - max_z;    // 0..7
        const float* ra = rbf_w + (long)(2 * kk)     * EDGE_DIM;
        const float* rb = rbf_w + (long)(2 * kk + 1) * EDGE_DIM;
        float sa = 0.0f, sb = 0.0f;
#pragma unroll 8
        for (int k = 0; k < EDGE_DIM; ++k) {
            const float wkd = edge_w[(long)(2 * NODE_DIM + k) * EDGE_DIM + d];
            sa += ra[k] * wkd;
            sb += rb[k] * wkd;
        }
        h2 v; v.x = (_Float16)sa; v.y = (_Float16)sb;
        w3h[kk * EDGE_DIM + d] = v;
    }
}

// ---------------------------------------------------------------------------
// zpair[e] = z[idx_j[e]] | (z[idx_i[e]] << 16)
// ---------------------------------------------------------------------------
__global__ void precompute_zpair(const int* __restrict__ z,
                                 const int* __restrict__ idx_i,
                                 const int* __restrict__ idx_j,
                                 int* __restrict__ zpair,
                                 int n_edges) {
    const int e = blockIdx.x * blockDim.x + threadIdx.x;
    if (e < n_edges) {
        const int zj = z[idx_j[e]];
        const int zi = z[idx_i[e]];
        zpair[e] = (zj & 0xffff) | (zi << 16);
    }
}

// ---------------------------------------------------------------------------
// Main kernel: LDS = fp16 table ONLY (51.2 KB -> 3 blocks/CU, 24 waves/CU).
// R7's chunk-ahead prefetch pipeline kept verbatim, but the 16-edge rbf +
// zpair staging lives in per-lane REGISTERS (lane L holds quarter-row L&3 of
// edge L>>2, packed fp16; lane L also holds zpair[base+(L&15)]).  Compute
// retrieves via __shfl.  Contraction = v_dot2_f32_f16 vs pair-packed w3h.
// 2 edges per step (lane halves), one float4 of the output row per lane.
// No in-loop barriers.
// ---------------------------------------------------------------------------
template <bool PRE>
__global__ void __launch_bounds__(BLOCK, 6) edge_main(
        const float* __restrict__ rbf,
        const int*   __restrict__ zpair,
        const int*   __restrict__ z,
        const int*   __restrict__ idx_i,
        const int*   __restrict__ idx_j,
        const h2*    __restrict__ tabg,    // 2*MAXZ rows of 64 h2
        const h2*    __restrict__ w3h,     // 8*128 h2
        float* __restrict__ out,
        int n_edges) {
    __shared__ h2 sTab[2 * MAXZ * 64];                 // 51200 B, only LDS

    const int tid  = threadIdx.x;
    const int lane = tid & 63;
    const int sub  = lane & 31;
    const int half = lane >> 5;

    // pair-packed w slice for this lane's 4 output cols -> 32 VGPRs
    h2 w[8][4];
#pragma unroll
    for (int kk = 0; kk < 8; ++kk) {
        const uint4 u = *reinterpret_cast<const uint4*>(
            &w3h[kk * EDGE_DIM + (sub << 2)]);
        w[kk][0] = __builtin_bit_cast(h2, u.x);
        w[kk][1] = __builtin_bit_cast(h2, u.y);
        w[kk][2] = __builtin_bit_cast(h2, u.z);
        w[kk][3] = __builtin_bit_cast(h2, u.w);
    }

    // cooperative copy of the table into LDS (3200 uint4)
    {
        const uint4* src = reinterpret_cast<const uint4*>(tabg);
        uint4*       dst = reinterpret_cast<uint4*>(sTab);
        for (int i = tid; i < (2 * MAXZ * EDGE_DIM) / 8; i += BLOCK)
            dst[i] = src[i];
    }
    __syncthreads();   // only barrier

    // contiguous chunk range for this wave
    const int W   = gridDim.x * NWAVE;
    const int gw  = blockIdx.x * NWAVE + (tid >> 6);
    const int nmc = (n_edges + MC - 1) / MC;
    const int mlo = (int)(((long)gw * nmc) / W);
    const int mhi = (int)(((long)(gw + 1) * nmc) / W);
    if (mlo >= mhi) return;

    const fx4* rbf4 = reinterpret_cast<const fx4*>(rbf);
    const int  emax = n_edges - 1;
    const int  eoff = lane >> 2;        // which of the 16 edges this lane stages
    const int  eqtr = lane & 3;         // which quarter-row this lane stages
    const int  zoff = lane & 15;        // which zpair this lane stages

#define GETZP(E) (PRE ? zpair[(E)] \
                      : ((z[idx_j[(E)]] & 0xffff) | (z[idx_i[(E)]] << 16)))
#define CLAMP(E) ((E) < emax ? (E) : emax)

    // ---- prologue: stage chunk mlo into registers ----
    int rs0, rs1, zs;
    {
        const int e = CLAMP(mlo * MC + eoff);
        const fx4 v = __builtin_nontemporal_load(rbf4 + (long)e * 4 + eqtr);
        rs0 = pk16i(v.x, v.y);
        rs1 = pk16i(v.z, v.w);
        zs  = GETZP(CLAMP(mlo * MC + zoff));
    }

    for (int m = mlo; m < mhi; ++m) {
        const bool hasn = (m + 1) < mhi;

        // ---- issue next-chunk loads first (held in regs until rotation) ----
        fx4 nv = (fx4)0.0f;
        int nz = 0;
        if (hasn) {
            const int e = CLAMP((m + 1) * MC + eoff);
            nv = __builtin_nontemporal_load(rbf4 + (long)e * 4 + eqtr);
            nz = GETZP(CLAMP((m + 1) * MC + zoff));
        }

        // ---- compute the 16 edges of chunk m from register staging ----
        const int base = m * MC;
#pragma unroll 2
        for (int s = 0; s < MC / 2; ++s) {
            const int el = (s << 1) | half;       // 0..15, this lane's edge
            const int eg = base + el;

            // zpair broadcast from staging lane el
            const int zp = __shfl(zs, el);
            const int zj = zp & 0xffff;
            const int zi = zp >> 16;

            // table rows (LDS, 8 B each)
            const h4 tj = *reinterpret_cast<const h4*>(
                &sTab[zj * 64 + (sub << 1)]);
            const h4 ti = *reinterpret_cast<const h4*>(
                &sTab[(MAXZ + zi) * 64 + (sub << 1)]);

            // rbf row: 8 packed-h2 dwords from staging lanes el*4 .. el*4+3
            h2 rb[8];
#pragma unroll
            for (int t = 0; t < 8; ++t) {
                const int src = (el << 2) | (t >> 1);
                const int d   = __shfl((t & 1) ? rs1 : rs0, src);
                rb[t] = __builtin_bit_cast(h2, d);
            }

            // acc init = t1[zj] + t2[zi] (packed), widen to fp32
            const h4 t = tj + ti;
            float a0 = (float)t[0], a1 = (float)t[1];
            float a2 = (float)t[2], a3 = (float)t[3];

#pragma unroll
            for (int kk = 0; kk < 8; ++kk) {
                a0 = fdot2f(rb[kk], w[kk][0], a0);
                a1 = fdot2f(rb[kk], w[kk][1], a1);
                a2 = fdot2f(rb[kk], w[kk][2], a2);
                a3 = fdot2f(rb[kk], w[kk][3], a3);
            }

            // swish via fast rcp
            fx4 o;
            o.x = a0 * __builtin_amdgcn_rcpf(1.0f + __expf(-a0));
            o.y = a1 * __builtin_amdgcn_rcpf(1.0f + __expf(-a1));
            o.z = a2 * __builtin_amdgcn_rcpf(1.0f + __expf(-a2));
            o.w = a3 * __builtin_amdgcn_rcpf(1.0f + __expf(-a3));

            if (eg <= emax)
                *reinterpret_cast<fx4*>(
                    &out[(size_t)eg * EDGE_DIM + (sub << 2)]) = o;
        }

        // ---- rotate staging ----
        if (hasn) {
            rs0 = pk16i(nv.x, nv.y);
            rs1 = pk16i(nv.z, nv.w);
            zs  = nz;
        }
    }
#undef GETZP
#undef CLAMP
}

extern "C" void kernel_launch(void* const* d_in, const int* in_sizes, int n_in,
                              void* d_out, int out_size, void* d_ws, size_t ws_size,
                              hipStream_t stream) {
    const int*   zp          = (const int*)  d_in[0];
    const float* rbf         = (const float*)d_in[1];
    const int*   idx_i       = (const int*)  d_in[2];
    const int*   idx_j       = (const int*)  d_in[3];
    const float* embed_table = (const float*)d_in[4];
    const float* rbf_w       = (const float*)d_in[5];
    const float* edge_w      = (const float*)d_in[6];
    const float* edge_b      = (const float*)d_in[7];

    int max_z = in_sizes[4] / NODE_DIM;           // 100
    if (max_z > MAXZ) max_z = MAXZ;
    const int n_edges = in_sizes[2];              // 800000

    const size_t tab_bytes = (size_t)2 * MAXZ * EDGE_DIM * sizeof(__half); // 51200
    const size_t w3h_bytes = (size_t)8 * EDGE_DIM * sizeof(h2);            // 4096
    __half* tH    = (__half*)d_ws;
    h2*     w3h   = (h2*)((char*)d_ws + tab_bytes);
    int*    zpair = (int*)((char*)d_ws + tab_bytes + w3h_bytes);
    const int use_zpair =
        (ws_size >= tab_bytes + w3h_bytes + (size_t)n_edges * sizeof(int)) ? 1 : 0;
    float* out = (float*)d_out;

    precompute_tables<<<max_z + 8, EDGE_DIM, 0, stream>>>(
        embed_table, edge_w, edge_b, rbf_w, tH, w3h, max_z);
    if (use_zpair)
        precompute_zpair<<<(n_edges + 255) / 256, 256, 0, stream>>>(
            zp, idx_i, idx_j, zpair, n_edges);

    const int grid = 768;   // 3 blocks/CU (LDS 51.2 KB each)
    if (use_zpair)
        edge_main<true><<<grid, BLOCK, 0, stream>>>(rbf, zpair, zp, idx_i, idx_j,
                                                    (const h2*)tH, w3h, out, n_edges);
    else
        edge_main<false><<<grid, BLOCK, 0, stream>>>(rbf, zpair, zp, idx_i, idx_j,
                                                     (const h2*)tH, w3h, out, n_edges);
}

// Round 11
// 107.542 us; speedup vs baseline: 1.8179x; 1.1837x over previous
//
#include <hip/hip_runtime.h>
#include <hip/hip_fp16.h>

#define NODE_DIM 128
#define EDGE_DIM 128
#define N_RADIAL 16
#define MAXZ     100
#define BLOCK    512
#define NWAVE    (BLOCK / 64)
#define MC       16            // edges per wave-private chunk (regs, not LDS)

typedef _Float16 h2  __attribute__((ext_vector_type(2)));
typedef _Float16 h4  __attribute__((ext_vector_type(4)));
typedef float    fx4 __attribute__((ext_vector_type(4)));

__device__ __forceinline__ float fdot2f(h2 a, h2 b, float c) {
#if __has_builtin(__builtin_amdgcn_fdot2)
    return __builtin_amdgcn_fdot2(a, b, c, false);
#else
    return c + (float)a.x * (float)b.x + (float)a.y * (float)b.y;
#endif
}

__device__ __forceinline__ int pk16i(float x, float y) {
#if __has_builtin(__builtin_amdgcn_cvt_pkrtz)
    return __builtin_bit_cast(int, __builtin_amdgcn_cvt_pkrtz(x, y));
#else
    h2 v; v.x = (_Float16)x; v.y = (_Float16)y;
    return __builtin_bit_cast(int, v);
#endif
}

// ---------------------------------------------------------------------------
// Fused precompute.
//  blocks [0, max_z)            : fp16 node tables t1/t2
//  blocks [max_z, max_z+8)      : pair-packed fp16 rbf matrix w3h
//  blocks [max_z+8, ...)        : zpair[e] = z[idx_j[e]] | (z[idx_i[e]]<<16)
// ---------------------------------------------------------------------------
__global__ void precompute_all(const float* __restrict__ embed_table,
                               const float* __restrict__ edge_w,
                               const float* __restrict__ edge_b,
                               const float* __restrict__ rbf_w,
                               const int*   __restrict__ z,
                               const int*   __restrict__ idx_i,
                               const int*   __restrict__ idx_j,
                               __half* __restrict__ tH,
                               h2* __restrict__ w3h,
                               int* __restrict__ zpair,
                               int max_z, int n_edges, int do_zpair) {
    const int d = threadIdx.x;
    if ((int)blockIdx.x < max_z) {
        const int r = blockIdx.x;
        float s1 = edge_b[d];
        float s2 = 0.0f;
        const float* er = embed_table + (long)r * NODE_DIM;
#pragma unroll 8
        for (int k = 0; k < NODE_DIM; ++k) {
            const float e = er[k];
            s1 += e * edge_w[(long)k * EDGE_DIM + d];
            s2 += e * edge_w[(long)(NODE_DIM + k) * EDGE_DIM + d];
        }
        tH[(long)r * EDGE_DIM + d]          = __float2half(s1);
        tH[(long)(MAXZ + r) * EDGE_DIM + d] = __float2half(s2);
    } else if ((int)blockIdx.x < max_z + 8) {
        const int kk = blockIdx.x - max_z;    // 0..7
        const float* ra = rbf_w + (long)(2 * kk)     * EDGE_DIM;
        const float* rb = rbf_w + (long)(2 * kk + 1) * EDGE_DIM;
        float sa = 0.0f, sb = 0.0f;
#pragma unroll 8
        for (int k = 0; k < EDGE_DIM; ++k) {
            const float wkd = edge_w[(long)(2 * NODE_DIM + k) * EDGE_DIM + d];
            sa += ra[k] * wkd;
            sb += rb[k] * wkd;
        }
        h2 v; v.x = (_Float16)sa; v.y = (_Float16)sb;
        w3h[kk * EDGE_DIM + d] = v;
    } else if (do_zpair) {
        const int e = (blockIdx.x - (max_z + 8)) * EDGE_DIM + d;
        if (e < n_edges) {
            const int zj = z[idx_j[e]];
            const int zi = z[idx_i[e]];
            zpair[e] = (zj & 0xffff) | (zi << 16);
        }
    }
}

// ---------------------------------------------------------------------------
// Main kernel: LDS = fp16 table ONLY (51.2 KB -> 3 blocks/CU, 24 waves/CU).
// Chunk-ahead register staging (lane L holds quarter-row L&3 of edge L>>2 as
// packed fp16, plus zpair[base+(L&15)]); compute retrieves via __shfl.
// rbf loads are NORMAL (L3-cacheable: 51.2 MB fits 256 MB L3, so timed graph
// replays hit L3).  out stores NONTEMPORAL (no-allocate: keep L3 clean for
// rbf).  No in-loop barriers, so nt-store ack latency is never waited on.
// ---------------------------------------------------------------------------
template <bool PRE>
__global__ void __launch_bounds__(BLOCK, 6) edge_main(
        const float* __restrict__ rbf,
        const int*   __restrict__ zpair,
        const int*   __restrict__ z,
        const int*   __restrict__ idx_i,
        const int*   __restrict__ idx_j,
        const h2*    __restrict__ tabg,    // 2*MAXZ rows of 64 h2
        const h2*    __restrict__ w3h,     // 8*128 h2
        float* __restrict__ out,
        int n_edges) {
    __shared__ h2 sTab[2 * MAXZ * 64];                 // 51200 B, only LDS

    const int tid  = threadIdx.x;
    const int lane = tid & 63;
    const int sub  = lane & 31;
    const int half = lane >> 5;

    // pair-packed w slice for this lane's 4 output cols -> 32 VGPRs
    h2 w[8][4];
#pragma unroll
    for (int kk = 0; kk < 8; ++kk) {
        const uint4 u = *reinterpret_cast<const uint4*>(
            &w3h[kk * EDGE_DIM + (sub << 2)]);
        w[kk][0] = __builtin_bit_cast(h2, u.x);
        w[kk][1] = __builtin_bit_cast(h2, u.y);
        w[kk][2] = __builtin_bit_cast(h2, u.z);
        w[kk][3] = __builtin_bit_cast(h2, u.w);
    }

    // cooperative copy of the table into LDS (3200 uint4)
    {
        const uint4* src = reinterpret_cast<const uint4*>(tabg);
        uint4*       dst = reinterpret_cast<uint4*>(sTab);
        for (int i = tid; i < (2 * MAXZ * EDGE_DIM) / 8; i += BLOCK)
            dst[i] = src[i];
    }
    __syncthreads();   // only barrier

    // contiguous chunk range for this wave
    const int W   = gridDim.x * NWAVE;
    const int gw  = blockIdx.x * NWAVE + (tid >> 6);
    const int nmc = (n_edges + MC - 1) / MC;
    const int mlo = (int)(((long)gw * nmc) / W);
    const int mhi = (int)(((long)(gw + 1) * nmc) / W);
    if (mlo >= mhi) return;

    const fx4* rbf4 = reinterpret_cast<const fx4*>(rbf);
    const int  emax = n_edges - 1;
    const int  eoff = lane >> 2;        // which of the 16 edges this lane stages
    const int  eqtr = lane & 3;         // which quarter-row this lane stages
    const int  zoff = lane & 15;        // which zpair this lane stages

#define GETZP(E) (PRE ? zpair[(E)] \
                      : ((z[idx_j[(E)]] & 0xffff) | (z[idx_i[(E)]] << 16)))
#define CLAMP(E) ((E) < emax ? (E) : emax)

    // ---- prologue: stage chunk mlo into registers ----
    int rs0, rs1, zs;
    {
        const int e = CLAMP(mlo * MC + eoff);
        const fx4 v = rbf4[(long)e * 4 + eqtr];        // cached load (L3-hot)
        rs0 = pk16i(v.x, v.y);
        rs1 = pk16i(v.z, v.w);
        zs  = GETZP(CLAMP(mlo * MC + zoff));
    }

    for (int m = mlo; m < mhi; ++m) {
        const bool hasn = (m + 1) < mhi;

        // ---- issue next-chunk loads first (held in regs until rotation) ----
        fx4 nv = (fx4)0.0f;
        int nz = 0;
        if (hasn) {
            const int e = CLAMP((m + 1) * MC + eoff);
            nv = rbf4[(long)e * 4 + eqtr];             // cached load (L3-hot)
            nz = GETZP(CLAMP((m + 1) * MC + zoff));
        }

        // ---- compute the 16 edges of chunk m from register staging ----
        const int base = m * MC;
#pragma unroll 2
        for (int s = 0; s < MC / 2; ++s) {
            const int el = (s << 1) | half;       // 0..15, this lane's edge
            const int eg = base + el;

            // zpair broadcast from staging lane el
            const int zp = __shfl(zs, el);
            const int zj = zp & 0xffff;
            const int zi = zp >> 16;

            // table rows (LDS, 8 B each)
            const h4 tj = *reinterpret_cast<const h4*>(
                &sTab[zj * 64 + (sub << 1)]);
            const h4 ti = *reinterpret_cast<const h4*>(
                &sTab[(MAXZ + zi) * 64 + (sub << 1)]);

            // rbf row: 8 packed-h2 dwords from staging lanes el*4 .. el*4+3
            h2 rb[8];
#pragma unroll
            for (int t = 0; t < 8; ++t) {
                const int src = (el << 2) | (t >> 1);
                const int d   = __shfl((t & 1) ? rs1 : rs0, src);
                rb[t] = __builtin_bit_cast(h2, d);
            }

            // acc init = t1[zj] + t2[zi] (packed), widen to fp32
            const h4 t = tj + ti;
            float a0 = (float)t[0], a1 = (float)t[1];
            float a2 = (float)t[2], a3 = (float)t[3];

#pragma unroll
            for (int kk = 0; kk < 8; ++kk) {
                a0 = fdot2f(rb[kk], w[kk][0], a0);
                a1 = fdot2f(rb[kk], w[kk][1], a1);
                a2 = fdot2f(rb[kk], w[kk][2], a2);
                a3 = fdot2f(rb[kk], w[kk][3], a3);
            }

            // swish via fast rcp
            fx4 o;
            o.x = a0 * __builtin_amdgcn_rcpf(1.0f + __expf(-a0));
            o.y = a1 * __builtin_amdgcn_rcpf(1.0f + __expf(-a1));
            o.z = a2 * __builtin_amdgcn_rcpf(1.0f + __expf(-a2));
            o.w = a3 * __builtin_amdgcn_rcpf(1.0f + __expf(-a3));

            if (eg <= emax)
                __builtin_nontemporal_store(o, reinterpret_cast<fx4*>(
                    &out[(size_t)eg * EDGE_DIM + (sub << 2)]));
        }

        // ---- rotate staging ----
        if (hasn) {
            rs0 = pk16i(nv.x, nv.y);
            rs1 = pk16i(nv.z, nv.w);
            zs  = nz;
        }
    }
#undef GETZP
#undef CLAMP
}

extern "C" void kernel_launch(void* const* d_in, const int* in_sizes, int n_in,
                              void* d_out, int out_size, void* d_ws, size_t ws_size,
                              hipStream_t stream) {
    const int*   zp          = (const int*)  d_in[0];
    const float* rbf         = (const float*)d_in[1];
    const int*   idx_i       = (const int*)  d_in[2];
    const int*   idx_j       = (const int*)  d_in[3];
    const float* embed_table = (const float*)d_in[4];
    const float* rbf_w       = (const float*)d_in[5];
    const float* edge_w      = (const float*)d_in[6];
    const float* edge_b      = (const float*)d_in[7];

    int max_z = in_sizes[4] / NODE_DIM;           // 100
    if (max_z > MAXZ) max_z = MAXZ;
    const int n_edges = in_sizes[2];              // 800000

    const size_t tab_bytes = (size_t)2 * MAXZ * EDGE_DIM * sizeof(__half); // 51200
    const size_t w3h_bytes = (size_t)8 * EDGE_DIM * sizeof(h2);            // 4096
    __half* tH    = (__half*)d_ws;
    h2*     w3h   = (h2*)((char*)d_ws + tab_bytes);
    int*    zpair = (int*)((char*)d_ws + tab_bytes + w3h_bytes);
    const int use_zpair =
        (ws_size >= tab_bytes + w3h_bytes + (size_t)n_edges * sizeof(int)) ? 1 : 0;
    float* out = (float*)d_out;

    const int zblocks = use_zpair ? (n_edges + EDGE_DIM - 1) / EDGE_DIM : 0;
    precompute_all<<<max_z + 8 + zblocks, EDGE_DIM, 0, stream>>>(
        embed_table, edge_w, edge_b, rbf_w, zp, idx_i, idx_j,
        tH, w3h, zpair, max_z, n_edges, use_zpair);

    const int grid = 768;   // 3 blocks/CU (LDS 51.2 KB each)
    if (use_zpair)
        edge_main<true><<<grid, BLOCK, 0, stream>>>(rbf, zpair, zp, idx_i, idx_j,
                                                    (const h2*)tH, w3h, out, n_edges);
    else
        edge_main<false><<<grid, BLOCK, 0, stream>>>(rbf, zpair, zp, idx_i, idx_j,
                                                     (const h2*)tH, w3h, out, n_edges);
}

// Round 12
// 106.522 us; speedup vs baseline: 1.8353x; 1.0096x over previous
//
#include <hip/hip_runtime.h>
#include <hip/hip_fp16.h>

#define NODE_DIM 128
#define EDGE_DIM 128
#define N_RADIAL 16
#define MAXZ     100
#define BLOCK    512
#define NWAVE    (BLOCK / 64)
#define MC       16            // edges per wave-private chunk (regs, not LDS)

typedef _Float16 h2  __attribute__((ext_vector_type(2)));
typedef float    fx2 __attribute__((ext_vector_type(2)));
typedef float    fx4 __attribute__((ext_vector_type(4)));

__device__ __forceinline__ float fdot2f(h2 a, h2 b, float c) {
#if __has_builtin(__builtin_amdgcn_fdot2)
    return __builtin_amdgcn_fdot2(a, b, c, false);
#else
    return c + (float)a.x * (float)b.x + (float)a.y * (float)b.y;
#endif
}

__device__ __forceinline__ int pk16i(float x, float y) {
#if __has_builtin(__builtin_amdgcn_cvt_pkrtz)
    return __builtin_bit_cast(int, __builtin_amdgcn_cvt_pkrtz(x, y));
#else
    h2 v; v.x = (_Float16)x; v.y = (_Float16)y;
    return __builtin_bit_cast(int, v);
#endif
}

// ---------------------------------------------------------------------------
// Fused precompute (unchanged from R11).
//  blocks [0, max_z)       : fp16 node tables t1/t2
//  blocks [max_z, max_z+8) : pair-packed fp16 rbf matrix w3h
//  blocks [max_z+8, ...)   : zpair[e] = z[idx_j[e]] | (z[idx_i[e]]<<16)
// ---------------------------------------------------------------------------
__global__ void precompute_all(const float* __restrict__ embed_table,
                               const float* __restrict__ edge_w,
                               const float* __restrict__ edge_b,
                               const float* __restrict__ rbf_w,
                               const int*   __restrict__ z,
                               const int*   __restrict__ idx_i,
                               const int*   __restrict__ idx_j,
                               __half* __restrict__ tH,
                               h2* __restrict__ w3h,
                               int* __restrict__ zpair,
                               int max_z, int n_edges, int do_zpair) {
    const int d = threadIdx.x;
    if ((int)blockIdx.x < max_z) {
        const int r = blockIdx.x;
        float s1 = edge_b[d];
        float s2 = 0.0f;
        const float* er = embed_table + (long)r * NODE_DIM;
#pragma unroll 8
        for (int k = 0; k < NODE_DIM; ++k) {
            const float e = er[k];
            s1 += e * edge_w[(long)k * EDGE_DIM + d];
            s2 += e * edge_w[(long)(NODE_DIM + k) * EDGE_DIM + d];
        }
        tH[(long)r * EDGE_DIM + d]          = __float2half(s1);
        tH[(long)(MAXZ + r) * EDGE_DIM + d] = __float2half(s2);
    } else if ((int)blockIdx.x < max_z + 8) {
        const int kk = blockIdx.x - max_z;    // 0..7
        const float* ra = rbf_w + (long)(2 * kk)     * EDGE_DIM;
        const float* rb = rbf_w + (long)(2 * kk + 1) * EDGE_DIM;
        float sa = 0.0f, sb = 0.0f;
#pragma unroll 8
        for (int k = 0; k < EDGE_DIM; ++k) {
            const float wkd = edge_w[(long)(2 * NODE_DIM + k) * EDGE_DIM + d];
            sa += ra[k] * wkd;
            sb += rb[k] * wkd;
        }
        h2 v; v.x = (_Float16)sa; v.y = (_Float16)sb;
        w3h[kk * EDGE_DIM + d] = v;
    } else if (do_zpair) {
        const int e = (blockIdx.x - (max_z + 8)) * EDGE_DIM + d;
        if (e < n_edges) {
            const int zj = z[idx_j[e]];
            const int zi = z[idx_i[e]];
            zpair[e] = (zj & 0xffff) | (zi << 16);
        }
    }
}

// ---------------------------------------------------------------------------
// Main kernel: LDS = fp16 table ONLY (51.2 KB -> 3 blocks/CU, 24 waves/CU).
// ONE edge per wave-step: all 64 lanes work on the same edge; lane owns 2
// output columns (2*lane, 2*lane+1).  All cross-lane distribution of staged
// rbf/zpair uses v_readlane (static source lane, VALU path, zero LDS-pipe
// cost); the uniform value feeds v_dot2_f32_f16 as its one SGPR operand.
// LDS-pipe ops drop to 2 ds_read_b32 per edge (table rows, conflict-free).
// Staging pipeline (chunk-ahead, registers), cached rbf loads (L3-resident
// across graph replays), nontemporal stores (keep L3 clean) - all kept.
// ---------------------------------------------------------------------------
template <bool PRE>
__global__ void __launch_bounds__(BLOCK, 6) edge_main(
        const float* __restrict__ rbf,
        const int*   __restrict__ zpair,
        const int*   __restrict__ z,
        const int*   __restrict__ idx_i,
        const int*   __restrict__ idx_j,
        const h2*    __restrict__ tabg,    // 2*MAXZ rows of 64 h2
        const h2*    __restrict__ w3h,     // 8*128 h2
        float* __restrict__ out,
        int n_edges) {
    __shared__ h2 sTab[2 * MAXZ * 64];                 // 51200 B, only LDS

    const int tid  = threadIdx.x;
    const int lane = tid & 63;

    // this lane's 2 output cols: w[kk][0] = cols(2kk,2kk+1)@d=2lane, [1]@2lane+1
    h2 w[8][2];
#pragma unroll
    for (int kk = 0; kk < 8; ++kk) {
        const uint2 u = *reinterpret_cast<const uint2*>(
            &w3h[kk * EDGE_DIM + 2 * lane]);
        w[kk][0] = __builtin_bit_cast(h2, u.x);
        w[kk][1] = __builtin_bit_cast(h2, u.y);
    }

    // cooperative copy of the table into LDS (3200 uint4)
    {
        const uint4* src = reinterpret_cast<const uint4*>(tabg);
        uint4*       dst = reinterpret_cast<uint4*>(sTab);
        for (int i = tid; i < (2 * MAXZ * EDGE_DIM) / 8; i += BLOCK)
            dst[i] = src[i];
    }
    __syncthreads();   // only barrier

    // contiguous chunk range for this wave
    const int W   = gridDim.x * NWAVE;
    const int gw  = blockIdx.x * NWAVE + (tid >> 6);
    const int nmc = (n_edges + MC - 1) / MC;
    const int mlo = (int)(((long)gw * nmc) / W);
    const int mhi = (int)(((long)(gw + 1) * nmc) / W);
    if (mlo >= mhi) return;

    const fx4* rbf4 = reinterpret_cast<const fx4*>(rbf);
    const int  emax = n_edges - 1;
    const int  eoff = lane >> 2;        // which of the 16 edges this lane stages
    const int  eqtr = lane & 3;         // which quarter-row this lane stages
    const int  zoff = lane & 15;        // which zpair this lane stages

#define GETZP(E) (PRE ? zpair[(E)] \
                      : ((z[idx_j[(E)]] & 0xffff) | (z[idx_i[(E)]] << 16)))
#define CLAMP(E) ((E) < emax ? (E) : emax)

    // ---- prologue: stage chunk mlo into registers ----
    int rs0, rs1, zs;
    {
        const int e = CLAMP(mlo * MC + eoff);
        const fx4 v = rbf4[(long)e * 4 + eqtr];        // cached load (L3-hot)
        rs0 = pk16i(v.x, v.y);
        rs1 = pk16i(v.z, v.w);
        zs  = GETZP(CLAMP(mlo * MC + zoff));
    }

    for (int m = mlo; m < mhi; ++m) {
        const bool hasn = (m + 1) < mhi;

        // ---- issue next-chunk loads first (held in regs until rotation) ----
        fx4 nv = (fx4)0.0f;
        int nz = 0;
        if (hasn) {
            const int e = CLAMP((m + 1) * MC + eoff);
            nv = rbf4[(long)e * 4 + eqtr];             // cached load (L3-hot)
            nz = GETZP(CLAMP((m + 1) * MC + zoff));
        }

        // ---- compute the 16 edges of chunk m, one edge per wave-step ----
        const int base = m * MC;
#pragma unroll
        for (int s = 0; s < MC; ++s) {
            const int eg = base + s;

            // zpair broadcast (uniform, static lane s)
            const int zp = __builtin_amdgcn_readlane(zs, s);
            const int zj = zp & 0xffff;
            const int zi = zp >> 16;

            // table h2 for this lane's 2 cols (2 x ds_read_b32, 2-way alias)
            const h2 tj = sTab[zj * 64 + lane];
            const h2 ti = sTab[(MAXZ + zi) * 64 + lane];

            // rbf row: 8 packed-h2 dwords broadcast from static lanes
            h2 rb[8];
#pragma unroll
            for (int t = 0; t < 8; ++t) {
                const int src = (s << 2) | (t >> 1);
                const int d   = __builtin_amdgcn_readlane((t & 1) ? rs1 : rs0,
                                                          src);
                rb[t] = __builtin_bit_cast(h2, d);
            }

            // acc init = t1[zj] + t2[zi] (packed fp16 add), widen to fp32
            const h2 t = tj + ti;
            float a0 = (float)t.x;
            float a1 = (float)t.y;

#pragma unroll
            for (int kk = 0; kk < 8; ++kk) {
                a0 = fdot2f(rb[kk], w[kk][0], a0);
                a1 = fdot2f(rb[kk], w[kk][1], a1);
            }

            // swish via fast rcp
            fx2 o;
            o.x = a0 * __builtin_amdgcn_rcpf(1.0f + __expf(-a0));
            o.y = a1 * __builtin_amdgcn_rcpf(1.0f + __expf(-a1));

            if (eg <= emax)
                __builtin_nontemporal_store(o, reinterpret_cast<fx2*>(
                    &out[(size_t)eg * EDGE_DIM + 2 * lane]));
        }

        // ---- rotate staging ----
        if (hasn) {
            rs0 = pk16i(nv.x, nv.y);
            rs1 = pk16i(nv.z, nv.w);
            zs  = nz;
        }
    }
#undef GETZP
#undef CLAMP
}

extern "C" void kernel_launch(void* const* d_in, const int* in_sizes, int n_in,
                              void* d_out, int out_size, void* d_ws, size_t ws_size,
                              hipStream_t stream) {
    const int*   zp          = (const int*)  d_in[0];
    const float* rbf         = (const float*)d_in[1];
    const int*   idx_i       = (const int*)  d_in[2];
    const int*   idx_j       = (const int*)  d_in[3];
    const float* embed_table = (const float*)d_in[4];
    const float* rbf_w       = (const float*)d_in[5];
    const float* edge_w      = (const float*)d_in[6];
    const float* edge_b      = (const float*)d_in[7];

    int max_z = in_sizes[4] / NODE_DIM;           // 100
    if (max_z > MAXZ) max_z = MAXZ;
    const int n_edges = in_sizes[2];              // 800000

    const size_t tab_bytes = (size_t)2 * MAXZ * EDGE_DIM * sizeof(__half); // 51200
    const size_t w3h_bytes = (size_t)8 * EDGE_DIM * sizeof(h2);            // 4096
    __half* tH    = (__half*)d_ws;
    h2*     w3h   = (h2*)((char*)d_ws + tab_bytes);
    int*    zpair = (int*)((char*)d_ws + tab_bytes + w3h_bytes);
    const int use_zpair =
        (ws_size >= tab_bytes + w3h_bytes + (size_t)n_edges * sizeof(int)) ? 1 : 0;
    float* out = (float*)d_out;

    const int zblocks = use_zpair ? (n_edges + EDGE_DIM - 1) / EDGE_DIM : 0;
    precompute_all<<<max_z + 8 + zblocks, EDGE_DIM, 0, stream>>>(
        embed_table, edge_w, edge_b, rbf_w, zp, idx_i, idx_j,
        tH, w3h, zpair, max_z, n_edges, use_zpair);

    const int grid = 768;   // 3 blocks/CU (LDS 51.2 KB each)
    if (use_zpair)
        edge_main<true><<<grid, BLOCK, 0, stream>>>(rbf, zpair, zp, idx_i, idx_j,
                                                    (const h2*)tH, w3h, out, n_edges);
    else
        edge_main<false><<<grid, BLOCK, 0, stream>>>(rbf, zpair, zp, idx_i, idx_j,
                                                     (const h2*)tH, w3h, out, n_edges);
}

// Round 13
// 104.086 us; speedup vs baseline: 1.8782x; 1.0234x over previous
//
#include <hip/hip_runtime.h>
#include <hip/hip_fp16.h>

#define NODE_DIM 128
#define EDGE_DIM 128
#define N_RADIAL 16
#define MAXZ     100
#define BLOCK    512
#define NWAVE    (BLOCK / 64)
#define MC       16            // edges per wave-private chunk (regs, not LDS)

typedef _Float16 h2  __attribute__((ext_vector_type(2)));
typedef float    fx2 __attribute__((ext_vector_type(2)));
typedef float    fx4 __attribute__((ext_vector_type(4)));

__device__ __forceinline__ float fdot2f(h2 a, h2 b, float c) {
#if __has_builtin(__builtin_amdgcn_fdot2)
    return __builtin_amdgcn_fdot2(a, b, c, false);
#else
    return c + (float)a.x * (float)b.x + (float)a.y * (float)b.y;
#endif
}

__device__ __forceinline__ int pk16i(float x, float y) {
#if __has_builtin(__builtin_amdgcn_cvt_pkrtz)
    return __builtin_bit_cast(int, __builtin_amdgcn_cvt_pkrtz(x, y));
#else
    h2 v; v.x = (_Float16)x; v.y = (_Float16)y;
    return __builtin_bit_cast(int, v);
#endif
}

// ---------------------------------------------------------------------------
// Precompute (tables only, 108 blocks).
//  blocks [0, max_z)       : fp16 node tables t1/t2
//  blocks [max_z, max_z+8) : pair-packed fp16 rbf matrix w3h
// ---------------------------------------------------------------------------
__global__ void precompute_tables(const float* __restrict__ embed_table,
                                  const float* __restrict__ edge_w,
                                  const float* __restrict__ edge_b,
                                  const float* __restrict__ rbf_w,
                                  __half* __restrict__ tH,
                                  h2* __restrict__ w3h,
                                  int max_z) {
    const int d = threadIdx.x;
    if ((int)blockIdx.x < max_z) {
        const int r = blockIdx.x;
        float s1 = edge_b[d];
        float s2 = 0.0f;
        const float* er = embed_table + (long)r * NODE_DIM;
#pragma unroll 8
        for (int k = 0; k < NODE_DIM; ++k) {
            const float e = er[k];
            s1 += e * edge_w[(long)k * EDGE_DIM + d];
            s2 += e * edge_w[(long)(NODE_DIM + k) * EDGE_DIM + d];
        }
        tH[(long)r * EDGE_DIM + d]          = __float2half(s1);
        tH[(long)(MAXZ + r) * EDGE_DIM + d] = __float2half(s2);
    } else {
        const int kk = blockIdx.x - max_z;    // 0..7
        const float* ra = rbf_w + (long)(2 * kk)     * EDGE_DIM;
        const float* rb = rbf_w + (long)(2 * kk + 1) * EDGE_DIM;
        float sa = 0.0f, sb = 0.0f;
#pragma unroll 8
        for (int k = 0; k < EDGE_DIM; ++k) {
            const float wkd = edge_w[(long)(2 * NODE_DIM + k) * EDGE_DIM + d];
            sa += ra[k] * wkd;
            sb += rb[k] * wkd;
        }
        h2 v; v.x = (_Float16)sa; v.y = (_Float16)sb;
        w3h[kk * EDGE_DIM + d] = v;
    }
}

// ---------------------------------------------------------------------------
// Main kernel: LDS = fp16 table ONLY (51.2 KB -> 3 blocks/CU, 24 waves/CU).
// ONE edge per wave-step; lane owns 2 output columns.  The idx->z 2-hop
// gather is FUSED into the chunk-ahead register staging (no prepass): it is
// issued a full chunk (~1600 issue-cycles) ahead, so the ~600-1200 cyc chain
// through L2 (z table = 200 KB, L2-resident) hides under compute + TLP.
// Cross-lane distribution via v_readlane (static lane, zero LDS-pipe cost).
// rbf loads cached (L3-resident across graph replays); out stores
// nontemporal (keep L3 clean for rbf).  No in-loop barriers.
// ---------------------------------------------------------------------------
__global__ void __launch_bounds__(BLOCK, 6) edge_main(
        const float* __restrict__ rbf,
        const int*   __restrict__ z,
        const int*   __restrict__ idx_i,
        const int*   __restrict__ idx_j,
        const h2*    __restrict__ tabg,    // 2*MAXZ rows of 64 h2
        const h2*    __restrict__ w3h,     // 8*128 h2
        float* __restrict__ out,
        int n_edges) {
    __shared__ h2 sTab[2 * MAXZ * 64];                 // 51200 B, only LDS

    const int tid  = threadIdx.x;
    const int lane = tid & 63;

    // this lane's 2 output cols of w3c (pair-packed over kk) -> 16 VGPRs
    h2 w[8][2];
#pragma unroll
    for (int kk = 0; kk < 8; ++kk) {
        const uint2 u = *reinterpret_cast<const uint2*>(
            &w3h[kk * EDGE_DIM + 2 * lane]);
        w[kk][0] = __builtin_bit_cast(h2, u.x);
        w[kk][1] = __builtin_bit_cast(h2, u.y);
    }

    // cooperative copy of the table into LDS (3200 uint4)
    {
        const uint4* src = reinterpret_cast<const uint4*>(tabg);
        uint4*       dst = reinterpret_cast<uint4*>(sTab);
        for (int i = tid; i < (2 * MAXZ * EDGE_DIM) / 8; i += BLOCK)
            dst[i] = src[i];
    }
    __syncthreads();   // only barrier

    // contiguous chunk range for this wave
    const int W   = gridDim.x * NWAVE;
    const int gw  = blockIdx.x * NWAVE + (tid >> 6);
    const int nmc = (n_edges + MC - 1) / MC;
    const int mlo = (int)(((long)gw * nmc) / W);
    const int mhi = (int)(((long)(gw + 1) * nmc) / W);
    if (mlo >= mhi) return;

    const fx4* rbf4 = reinterpret_cast<const fx4*>(rbf);
    const int  emax = n_edges - 1;
    const int  eoff = lane >> 2;        // which of the 16 edges this lane stages
    const int  eqtr = lane & 3;         // which quarter-row this lane stages
    const int  zoff = lane & 15;        // which edge's z this lane stages

#define GETZP(E) ((z[idx_j[(E)]] & 0xffff) | (z[idx_i[(E)]] << 16))
#define CLAMP(E) ((E) < emax ? (E) : emax)

    // ---- prologue: stage chunk mlo into registers ----
    int rs0, rs1, zs;
    {
        const int e = CLAMP(mlo * MC + eoff);
        const fx4 v = rbf4[(long)e * 4 + eqtr];        // cached load (L3-hot)
        rs0 = pk16i(v.x, v.y);
        rs1 = pk16i(v.z, v.w);
        zs  = GETZP(CLAMP(mlo * MC + zoff));
    }

    for (int m = mlo; m < mhi; ++m) {
        const bool hasn = (m + 1) < mhi;

        // ---- issue next-chunk loads first (held in regs until rotation) ----
        fx4 nv = (fx4)0.0f;
        int nz = 0;
        if (hasn) {
            const int e = CLAMP((m + 1) * MC + eoff);
            nv = rbf4[(long)e * 4 + eqtr];             // cached load (L3-hot)
            nz = GETZP(CLAMP((m + 1) * MC + zoff));
        }

        // ---- compute the 16 edges of chunk m, one edge per wave-step ----
        const int base = m * MC;
#pragma unroll
        for (int s = 0; s < MC; ++s) {
            const int eg = base + s;

            // z pair broadcast (uniform, static lane s)
            const int zp = __builtin_amdgcn_readlane(zs, s);
            const int zj = zp & 0xffff;
            const int zi = zp >> 16;

            // table h2 for this lane's 2 cols (2 x ds_read_b32, 2-way alias)
            const h2 tj = sTab[zj * 64 + lane];
            const h2 ti = sTab[(MAXZ + zi) * 64 + lane];

            // rbf row: 8 packed-h2 dwords broadcast from static lanes
            h2 rb[8];
#pragma unroll
            for (int t = 0; t < 8; ++t) {
                const int src = (s << 2) | (t >> 1);
                const int d   = __builtin_amdgcn_readlane((t & 1) ? rs1 : rs0,
                                                          src);
                rb[t] = __builtin_bit_cast(h2, d);
            }

            // acc init = t1[zj] + t2[zi] (packed fp16 add), widen to fp32
            const h2 t = tj + ti;
            float a0 = (float)t.x;
            float a1 = (float)t.y;

#pragma unroll
            for (int kk = 0; kk < 8; ++kk) {
                a0 = fdot2f(rb[kk], w[kk][0], a0);
                a1 = fdot2f(rb[kk], w[kk][1], a1);
            }

            // swish via fast rcp
            fx2 o;
            o.x = a0 * __builtin_amdgcn_rcpf(1.0f + __expf(-a0));
            o.y = a1 * __builtin_amdgcn_rcpf(1.0f + __expf(-a1));

            if (eg <= emax)
                __builtin_nontemporal_store(o, reinterpret_cast<fx2*>(
                    &out[(size_t)eg * EDGE_DIM + 2 * lane]));
        }

        // ---- rotate staging ----
        if (hasn) {
            rs0 = pk16i(nv.x, nv.y);
            rs1 = pk16i(nv.z, nv.w);
            zs  = nz;
        }
    }
#undef GETZP
#undef CLAMP
}

extern "C" void kernel_launch(void* const* d_in, const int* in_sizes, int n_in,
                              void* d_out, int out_size, void* d_ws, size_t ws_size,
                              hipStream_t stream) {
    const int*   zp          = (const int*)  d_in[0];
    const float* rbf         = (const float*)d_in[1];
    const int*   idx_i       = (const int*)  d_in[2];
    const int*   idx_j       = (const int*)  d_in[3];
    const float* embed_table = (const float*)d_in[4];
    const float* rbf_w       = (const float*)d_in[5];
    const float* edge_w      = (const float*)d_in[6];
    const float* edge_b      = (const float*)d_in[7];

    int max_z = in_sizes[4] / NODE_DIM;           // 100
    if (max_z > MAXZ) max_z = MAXZ;
    const int n_edges = in_sizes[2];              // 800000

    const size_t tab_bytes = (size_t)2 * MAXZ * EDGE_DIM * sizeof(__half); // 51200
    __half* tH  = (__half*)d_ws;
    h2*     w3h = (h2*)((char*)d_ws + tab_bytes);
    float*  out = (float*)d_out;

    precompute_tables<<<max_z + 8, EDGE_DIM, 0, stream>>>(
        embed_table, edge_w, edge_b, rbf_w, tH, w3h, max_z);

    const int grid = 768;   // 3 blocks/CU (LDS 51.2 KB each)
    edge_main<<<grid, BLOCK, 0, stream>>>(rbf, zp, idx_i, idx_j,
                                          (const h2*)tH, w3h, out, n_edges);
}